// Round 5
// baseline (754.311 us; speedup 1.0000x reference)
//
#include <hip/hip_runtime.h>
#include <hip/hip_bf16.h>

// (B,H,S,D) = (4,16,2048,128), causal.
constexpr int S_LEN = 2048;
constexpr int D_DIM = 128;
constexpr int NBH   = 64;                     // B*H
constexpr int NKT   = 32;                     // number of 64-key tiles
constexpr size_t TILE_SHORTS = 64 * 128;      // 8192 shorts = 16 KB per K or V^T tile
constexpr size_t PAIR_SHORTS = 2 * TILE_SHORTS;
constexpr size_t WS_NEEDED   = (size_t)NBH * NKT * PAIR_SHORTS * 2;  // 64 MB

typedef __attribute__((ext_vector_type(8))) short short8;  // 8 x bf16
typedef __attribute__((ext_vector_type(4))) float f32x4;   // MFMA acc

__device__ __forceinline__ short f2bf(float f) {
    unsigned u = __builtin_bit_cast(unsigned, f);
    u += 0x7fffu + ((u >> 16) & 1u);
    return (short)(u >> 16);
}

// Swizzled chunk positions (8-short chunks), baked into the GLOBAL tile image
// so that DMA (identity copy) reproduces them in LDS.  (Proven layouts.)
__device__ __forceinline__ int kpos(int dc, int key) { return dc ^ (key & 15); }
__device__ __forceinline__ int vpos(int kc, int d) {
    return kc ^ ((d >> 3) & 7) ^ (d & 7);
}

// ---------------- Preprocess: fp32 K/V -> bf16 swizzled tiles in ws ----------
__global__ __launch_bounds__(256)
void preprocess_kv(const float* __restrict__ K, const float* __restrict__ V,
                   short* __restrict__ ws) {
    __shared__ short sv[128 * 64];   // V^T staging for coalesced global writes
    const int tid = threadIdx.x;
    const int kt  = blockIdx.x;
    const int bh  = blockIdx.y;
    const size_t inbase = ((size_t)bh * S_LEN + (size_t)kt * 64) * D_DIM;
    short* wk = ws + ((size_t)bh * NKT + kt) * PAIR_SHORTS;
    short* wv = wk + TILE_SHORTS;

    for (int it = 0; it < 4; ++it) {
        const int idx = (it * 256 + tid) * 8;
        const int key = idx >> 7, d = idx & 127;
        const float* kp = K + inbase + (size_t)key * D_DIM + d;
        float4 a = *reinterpret_cast<const float4*>(kp);
        float4 b = *reinterpret_cast<const float4*>(kp + 4);
        short8 f;
        f[0]=f2bf(a.x); f[1]=f2bf(a.y); f[2]=f2bf(a.z); f[3]=f2bf(a.w);
        f[4]=f2bf(b.x); f[5]=f2bf(b.y); f[6]=f2bf(b.z); f[7]=f2bf(b.w);
        *reinterpret_cast<short8*>(&wk[key * 128 + (kpos(d >> 3, key) << 3)]) = f;
        const float* vp = V + inbase + (size_t)key * D_DIM + d;
        float4 c = *reinterpret_cast<const float4*>(vp);
        float4 e = *reinterpret_cast<const float4*>(vp + 4);
        float vals[8] = {c.x,c.y,c.z,c.w,e.x,e.y,e.z,e.w};
        for (int j = 0; j < 8; ++j) {
            const int dr = d + j;
            sv[dr * 64 + (vpos(key >> 3, dr) << 3) + (key & 7)] = f2bf(vals[j]);
        }
    }
    __syncthreads();
    for (int it = 0; it < 4; ++it) {
        const int off = (it * 256 + tid) * 8;
        *reinterpret_cast<short8*>(&wv[off]) =
            *reinterpret_cast<const short8*>(&sv[off]);
    }
}

// ---------------- Async copy helpers (global -> LDS, 16B/lane) ---------------
__device__ __forceinline__ void async_copy_1k(const short* gsrc, short* ldst,
                                              int lane) {
    __builtin_amdgcn_global_load_lds(
        (const __attribute__((address_space(1))) void*)(gsrc + lane * 8),
        (__attribute__((address_space(3))) void*)ldst, 16, 0, 0);
}
__device__ __forceinline__ void dma_tile16k(const short* gsrc, short* ldst,
                                            int wid, int lane) {
    for (int i = 0; i < 4; ++i) {
        const int s = wid * 4 + i;               // 16 x 1KB slices, 4 waves
        async_copy_1k(gsrc + s * 512, ldst + s * 512, lane);
    }
}

// ---------------- Main flash-attention kernel --------------------------------
// 128-row q-blocks (4 waves x 32 rows as two 16-row halves), unpaired: 16
// blocks/bh, 1024 blocks.  Halves K/V tile re-fetch traffic vs 64-row blocks
// (272 vs 528 tile-visits per bh).  XCD-grouping swizzle puts all 16 blocks
// of one bh on one XCD (its 1 MB tile-set lives in that L2) — r1-measured
// FETCH 268 MB vs 541.  Execution shape = r3's proven counted-vmcnt A/B/C:
//   A: vmcnt(4)+lgkm+barrier  -> drains K-DMA(kt); V-DMA(kt) stays flying
//   B: __syncthreads          -> drains V-DMA(kt) (window = QK + softmax)
//   C: lgkm-only barrier      -> K-DMA(kt+1) spans it (window = P + PV)
// LDS 48 KB, __launch_bounds__(256,3) -> 3 blocks/CU (12 waves/CU).
__global__ __launch_bounds__(256, 3)
void fa_causal_main(const float* __restrict__ Q, const short* __restrict__ ws,
                    float* __restrict__ Out) {
    __shared__ short sK [64 * 128];   // DMA image of K tile (swizzled)
    __shared__ short sVt[128 * 64];   // DMA image of V^T tile (swizzled)
    __shared__ short sP [128 * 64];   // P tile, XOR-swizzled, per-wave rows

    const int tid  = threadIdx.x;
    const int wid  = tid >> 6;
    const int lane = tid & 63;
    const int quad = lane >> 4;
    const int l16  = lane & 15;

    // XCD-grouping swizzle: linear id L = bx + 16*by; L%8 picks the XCD.
    // bh = (L&7)*8 + (L>>3)&7  -> all 16 blocks of a bh share L%8 (one XCD).
    // qt = 15 - (L>>6): longest blocks dispatch first.  Bijective.
    const int L   = blockIdx.x + (blockIdx.y << 4);
    const int bh  = ((L & 7) << 3) | ((L >> 3) & 7);
    const int qt  = 15 - (L >> 6);    // q super-tile, 128 rows
    const int q0  = qt * 128;
    const int kend = 2 * qt + 2;      // k-tiles 0 .. 2qt+1

    const size_t base = (size_t)bh * S_LEN * D_DIM;
    const short* tiles = ws + (size_t)bh * NKT * PAIR_SHORTS;
    const float scale = 0.08838834764831845f;  // 1/sqrt(128)

    // ---- Q loads FIRST (so consuming them waits only on themselves,
    //      leaving the 8 DMA ops below in flight), then K-DMA(0), V-DMA(0).
    float4 qa[2][4], qb[2][4];
    #pragma unroll
    for (int mh = 0; mh < 2; ++mh) {
        const float* qp = Q + base +
            (size_t)(q0 + wid * 32 + mh * 16 + l16) * D_DIM;
        for (int kk = 0; kk < 4; ++kk) {
            const int d0 = kk * 32 + quad * 8;
            qa[mh][kk] = *reinterpret_cast<const float4*>(qp + d0);
            qb[mh][kk] = *reinterpret_cast<const float4*>(qp + d0 + 4);
        }
    }
    dma_tile16k(tiles, sK, wid, lane);
    dma_tile16k(tiles + TILE_SHORTS, sVt, wid, lane);

    // ---- Q fragments (A-layout: m=l16, k=quad*8+j), pre-scaled ----
    short8 q_frag[2][4];
    #pragma unroll
    for (int mh = 0; mh < 2; ++mh)
        for (int kk = 0; kk < 4; ++kk) {
            short8 f;
            f[0]=f2bf(qa[mh][kk].x*scale); f[1]=f2bf(qa[mh][kk].y*scale);
            f[2]=f2bf(qa[mh][kk].z*scale); f[3]=f2bf(qa[mh][kk].w*scale);
            f[4]=f2bf(qb[mh][kk].x*scale); f[5]=f2bf(qb[mh][kk].y*scale);
            f[6]=f2bf(qb[mh][kk].z*scale); f[7]=f2bf(qb[mh][kk].w*scale);
            q_frag[mh][kk] = f;
        }

    f32x4 o_acc[2][8];
    #pragma unroll
    for (int mh = 0; mh < 2; ++mh)
        for (int i = 0; i < 8; ++i) o_acc[mh][i] = f32x4{0.f,0.f,0.f,0.f};
    float m_i[2][4], l_i[2][4];
    #pragma unroll
    for (int mh = 0; mh < 2; ++mh)
        for (int r = 0; r < 4; ++r) { m_i[mh][r] = -1e30f; l_i[mh][r] = 0.f; }

    for (int kt = 0; kt < kend; ++kt) {
        // A: drain the 4 oldest vmem ops = K-DMA(kt); keep V-DMA(kt)
        // (the 4 newest) in flight.  lgkm(0) for shuffle/LDS ordering.
        asm volatile("s_waitcnt vmcnt(4) lgkmcnt(0)" ::: "memory");
        __builtin_amdgcn_s_barrier();
        asm volatile("" ::: "memory");

        const int kb = kt * 64;

        #pragma unroll
        for (int mh = 0; mh < 2; ++mh) {
            const int rmin = q0 + wid * 32 + mh * 16;   // half's first q-row
            if (kb > rmin + 15) continue;               // fully masked half

            // ---- S = Q K^T (16 rows x 64 keys) ----
            f32x4 s_acc[4];
            for (int ct = 0; ct < 4; ++ct) {
                const int key = ct * 16 + l16;
                f32x4 acc = f32x4{0.f,0.f,0.f,0.f};
                for (int kk = 0; kk < 4; ++kk) {
                    short8 kf = *reinterpret_cast<const short8*>(
                        &sK[key * 128 + (kpos(kk * 4 + quad, key) << 3)]);
                    acc = __builtin_amdgcn_mfma_f32_16x16x32_bf16(q_frag[mh][kk], kf, acc, 0, 0, 0);
                }
                s_acc[ct] = acc;
            }

            // ---- Causal mask (tiles overlapping the diagonal) ----
            if (kb + 63 > rmin) {
                for (int ct = 0; ct < 4; ++ct) {
                    const int kg = kb + ct * 16 + l16;
                    for (int r = 0; r < 4; ++r)
                        if (kg > rmin + quad * 4 + r) s_acc[ct][r] = -1e30f;
                }
            }

            // ---- Online softmax (registers + 16-lane shuffles) ----
            float tm[4];
            for (int r = 0; r < 4; ++r)
                tm[r] = fmaxf(fmaxf(s_acc[0][r], s_acc[1][r]),
                              fmaxf(s_acc[2][r], s_acc[3][r]));
            for (int off = 1; off < 16; off <<= 1)
                for (int r = 0; r < 4; ++r)
                    tm[r] = fmaxf(tm[r], __shfl_xor(tm[r], off));
            float alpha[4], m_new[4], rs[4];
            for (int r = 0; r < 4; ++r) {
                m_new[r] = fmaxf(m_i[mh][r], tm[r]);
                alpha[r] = __expf(m_i[mh][r] - m_new[r]);
                rs[r] = 0.f;
            }
            for (int ct = 0; ct < 4; ++ct)
                for (int r = 0; r < 4; ++r) {
                    float p = __expf(s_acc[ct][r] - m_new[r]);
                    s_acc[ct][r] = p;
                    rs[r] += p;
                }
            for (int off = 1; off < 16; off <<= 1)
                for (int r = 0; r < 4; ++r)
                    rs[r] += __shfl_xor(rs[r], off);
            for (int r = 0; r < 4; ++r) {
                l_i[mh][r] = alpha[r] * l_i[mh][r] + rs[r];
                m_i[mh][r] = m_new[r];
            }
            for (int nt = 0; nt < 8; ++nt)
                for (int r = 0; r < 4; ++r)
                    o_acc[mh][nt][r] *= alpha[r];

            // ---- P -> sP (XOR-swizzled; same-wave write->read) ----
            for (int ct = 0; ct < 4; ++ct)
                for (int r = 0; r < 4; ++r) {
                    const int row = wid * 32 + mh * 16 + quad * 4 + r;
                    const int col = ct * 16 + l16;
                    sP[row * 64 + (((col >> 3) ^ (row & 7)) << 3) + (col & 7)]
                        = f2bf(s_acc[ct][r]);
                }
        }

        // B: __syncthreads -> vmcnt(0) drains V-DMA(kt) (the only
        // outstanding vmem), with the QK+softmax window behind it.
        // Also orders all QK reads of sK before the K-DMA below.
        __syncthreads();

        // K-DMA for kt+1: lands in sK across C, drained at next A.
        if (kt + 1 < kend)
            dma_tile16k(tiles + (size_t)(kt + 1) * PAIR_SHORTS, sK, wid, lane);

        // ---- O += P V (V-fragments reused across both halves) ----
        {
            const bool act0 = (kb <= q0 + wid * 32 + 15);
            const bool act1 = (kb <= q0 + wid * 32 + 16 + 15);
            const int pr0 = wid * 32 + l16;
            const int pr1 = wid * 32 + 16 + l16;
            short8 pf0[2], pf1[2];
            if (act0)
                for (int k2 = 0; k2 < 2; ++k2)
                    pf0[k2] = *reinterpret_cast<const short8*>(
                        &sP[pr0 * 64 + (((k2 * 4 + quad) ^ (pr0 & 7)) << 3)]);
            if (act1)
                for (int k2 = 0; k2 < 2; ++k2)
                    pf1[k2] = *reinterpret_cast<const short8*>(
                        &sP[pr1 * 64 + (((k2 * 4 + quad) ^ (pr1 & 7)) << 3)]);
            for (int nt = 0; nt < 8; ++nt) {
                const int vrow = nt * 16 + l16;
                for (int k2 = 0; k2 < 2; ++k2) {
                    short8 vf = *reinterpret_cast<const short8*>(
                        &sVt[vrow * 64 + (vpos(k2 * 4 + quad, vrow) << 3)]);
                    if (act0)
                        o_acc[0][nt] = __builtin_amdgcn_mfma_f32_16x16x32_bf16(pf0[k2], vf, o_acc[0][nt], 0, 0, 0);
                    if (act1)
                        o_acc[1][nt] = __builtin_amdgcn_mfma_f32_16x16x32_bf16(pf1[k2], vf, o_acc[1][nt], 0, 0, 0);
                }
            }
        }

        // C: lgkm-only barrier — orders all PV reads of sVt/sP before the
        // V-DMA below; the in-flight K-DMA(kt+1) is NOT drained here.
        asm volatile("s_waitcnt lgkmcnt(0)" ::: "memory");
        __builtin_amdgcn_s_barrier();
        asm volatile("" ::: "memory");

        // V-DMA for kt+1: drains at B(kt+1) with the QK+softmax window.
        if (kt + 1 < kend)
            dma_tile16k(tiles + (size_t)(kt + 1) * PAIR_SHORTS + TILE_SHORTS,
                        sVt, wid, lane);
    }

    // ---- Epilogue ----
    #pragma unroll
    for (int mh = 0; mh < 2; ++mh)
        for (int r = 0; r < 4; ++r) {
            const float inv = 1.0f / l_i[mh][r];
            const int qrow = q0 + wid * 32 + mh * 16 + quad * 4 + r;
            float* op = Out + base + (size_t)qrow * D_DIM;
            for (int nt = 0; nt < 8; ++nt)
                op[nt * 16 + l16] = o_acc[mh][nt][r] * inv;
        }
}

// ---------------- Fallback (round-2 kernel, used if ws too small) ------------
constexpr int SK_STRIDE  = 136;
constexpr int SVT_STRIDE = 72;
constexpr int SP_STRIDE  = 72;

__global__ __launch_bounds__(256, 4)
void fa_causal_fallback(const float* __restrict__ Q, const float* __restrict__ K,
                        const float* __restrict__ V, float* __restrict__ Out) {
    __shared__ short sK[64 * SK_STRIDE];
    __shared__ short sVt[128 * SVT_STRIDE];
    short* sP = sK;
    const int tid  = threadIdx.x;
    const int wid  = tid >> 6;
    const int lane = tid & 63;
    const int quad = lane >> 4;
    const int l16  = lane & 15;
    const int x  = blockIdx.x;
    const int bh = blockIdx.y;
    const size_t base = (size_t)bh * S_LEN * D_DIM;
    const float scale = 0.08838834764831845f;
    for (int pi = 0; pi < 2; ++pi) {
        const int qt = (pi == 0) ? (31 - x) : x;
        const int q0 = qt * 64;
        short8 q_frag[4];
        {
            const float* qp = Q + base + (size_t)(q0 + wid * 16 + l16) * D_DIM;
            for (int kk = 0; kk < 4; ++kk) {
                const int d0 = kk * 32 + quad * 8;
                float4 a = *reinterpret_cast<const float4*>(qp + d0);
                float4 b = *reinterpret_cast<const float4*>(qp + d0 + 4);
                short8 f;
                f[0]=f2bf(a.x*scale); f[1]=f2bf(a.y*scale);
                f[2]=f2bf(a.z*scale); f[3]=f2bf(a.w*scale);
                f[4]=f2bf(b.x*scale); f[5]=f2bf(b.y*scale);
                f[6]=f2bf(b.z*scale); f[7]=f2bf(b.w*scale);
                q_frag[kk] = f;
            }
        }
        f32x4 o_acc[8];
        for (int i = 0; i < 8; ++i) o_acc[i] = f32x4{0.f,0.f,0.f,0.f};
        float m_i[4], l_i[4];
        for (int r = 0; r < 4; ++r) { m_i[r] = -1e30f; l_i[r] = 0.f; }
        for (int kt = 0; kt <= qt; ++kt) {
            for (int it = 0; it < 4; ++it) {
                const int idx = (it * 256 + tid) * 8;
                const int key = idx >> 7, d = idx & 127;
                const float* kp = K + base + (size_t)(kt * 64 + key) * D_DIM + d;
                float4 a = *reinterpret_cast<const float4*>(kp);
                float4 b = *reinterpret_cast<const float4*>(kp + 4);
                short8 f;
                f[0]=f2bf(a.x); f[1]=f2bf(a.y); f[2]=f2bf(a.z); f[3]=f2bf(a.w);
                f[4]=f2bf(b.x); f[5]=f2bf(b.y); f[6]=f2bf(b.z); f[7]=f2bf(b.w);
                *reinterpret_cast<short8*>(&sK[key * SK_STRIDE + d]) = f;
            }
            for (int it = 0; it < 4; ++it) {
                const int idx = (it * 256 + tid) * 8;
                const int key = idx >> 7, d = idx & 127;
                const int kc = key >> 3, kw = key & 7;
                const float* vp = V + base + (size_t)(kt * 64 + key) * D_DIM + d;
                float4 a = *reinterpret_cast<const float4*>(vp);
                float4 b = *reinterpret_cast<const float4*>(vp + 4);
                float vals[8] = {a.x,a.y,a.z,a.w,b.x,b.y,b.z,b.w};
                const int rc = (d >> 3) & 7;
                const int cs = (kc ^ rc) * 8 + kw;
                for (int j = 0; j < 8; ++j)
                    sVt[(d + j) * SVT_STRIDE + cs] = f2bf(vals[j]);
            }
            __syncthreads();
            f32x4 s_acc[4];
            for (int ct = 0; ct < 4; ++ct) {
                f32x4 acc = f32x4{0.f,0.f,0.f,0.f};
                for (int kk = 0; kk < 4; ++kk) {
                    short8 kf = *reinterpret_cast<const short8*>(
                        &sK[(ct * 16 + l16) * SK_STRIDE + kk * 32 + quad * 8]);
                    acc = __builtin_amdgcn_mfma_f32_16x16x32_bf16(q_frag[kk], kf, acc, 0, 0, 0);
                }
                s_acc[ct] = acc;
            }
            if (kt == qt) {
                for (int ct = 0; ct < 4; ++ct) {
                    const int kg = ct * 16 + l16;
                    for (int r = 0; r < 4; ++r)
                        if (kg > wid * 16 + quad * 4 + r) s_acc[ct][r] = -1e30f;
                }
            }
            float tm[4];
            for (int r = 0; r < 4; ++r)
                tm[r] = fmaxf(fmaxf(s_acc[0][r], s_acc[1][r]),
                              fmaxf(s_acc[2][r], s_acc[3][r]));
            for (int off = 1; off < 16; off <<= 1)
                for (int r = 0; r < 4; ++r)
                    tm[r] = fmaxf(tm[r], __shfl_xor(tm[r], off));
            float alpha[4], m_new[4], rs[4];
            for (int r = 0; r < 4; ++r) {
                m_new[r] = fmaxf(m_i[r], tm[r]);
                alpha[r] = __expf(m_i[r] - m_new[r]);
                rs[r] = 0.f;
            }
            for (int ct = 0; ct < 4; ++ct)
                for (int r = 0; r < 4; ++r) {
                    float p = __expf(s_acc[ct][r] - m_new[r]);
                    s_acc[ct][r] = p;
                    rs[r] += p;
                }
            for (int off = 1; off < 16; off <<= 1)
                for (int r = 0; r < 4; ++r)
                    rs[r] += __shfl_xor(rs[r], off);
            for (int r = 0; r < 4; ++r) {
                l_i[r] = alpha[r] * l_i[r] + rs[r];
                m_i[r] = m_new[r];
            }
            for (int nt = 0; nt < 8; ++nt)
                for (int r = 0; r < 4; ++r)
                    o_acc[nt][r] *= alpha[r];
            __syncthreads();
            for (int ct = 0; ct < 4; ++ct)
                for (int r = 0; r < 4; ++r) {
                    const int row = wid * 16 + quad * 4 + r;
                    const int col = ct * 16 + l16;
                    sP[row * SP_STRIDE + (((col >> 3) ^ ((row >> 2) & 7)) << 3) + (col & 7)]
                        = f2bf(s_acc[ct][r]);
                }
            {
                const int prow = wid * 16 + l16;
                const int pxr  = (prow >> 2) & 7;
                for (int nt = 0; nt < 8; ++nt) {
                    const int vrow = nt * 16 + l16;
                    const int vxr  = (vrow >> 3) & 7;
                    for (int k2 = 0; k2 < 2; ++k2) {
                        const int chunk = k2 * 4 + quad;
                        short8 pf = *reinterpret_cast<const short8*>(
                            &sP[prow * SP_STRIDE + ((chunk ^ pxr) << 3)]);
                        short8 vf = *reinterpret_cast<const short8*>(
                            &sVt[vrow * SVT_STRIDE + ((chunk ^ vxr) << 3)]);
                        o_acc[nt] = __builtin_amdgcn_mfma_f32_16x16x32_bf16(pf, vf, o_acc[nt], 0, 0, 0);
                    }
                }
            }
            __syncthreads();
        }
        for (int nt = 0; nt < 8; ++nt)
            for (int r = 0; r < 4; ++r) {
                const int qrow = q0 + wid * 16 + quad * 4 + r;
                Out[base + (size_t)qrow * D_DIM + nt * 16 + l16] = o_acc[nt][r] / l_i[r];
            }
    }
}

extern "C" void kernel_launch(void* const* d_in, const int* in_sizes, int n_in,
                              void* d_out, int out_size, void* d_ws, size_t ws_size,
                              hipStream_t stream) {
    const float* Q = (const float*)d_in[0];
    const float* K = (const float*)d_in[1];
    const float* V = (const float*)d_in[2];
    float* Out = (float*)d_out;

    if (ws_size >= WS_NEEDED) {
        short* ws = (short*)d_ws;
        preprocess_kv<<<dim3(NKT, NBH), 256, 0, stream>>>(K, V, ws);
        fa_causal_main<<<dim3(16, NBH), 256, 0, stream>>>(Q, ws, Out);
    } else {
        fa_causal_fallback<<<dim3(16, NBH), 256, 0, stream>>>(Q, K, V, Out);
    }
}

// Round 6
// 400.807 us; speedup vs baseline: 1.8820x; 1.8820x over previous
//
#include <hip/hip_runtime.h>
#include <hip/hip_bf16.h>

// (B,H,S,D) = (4,16,2048,128), causal.
constexpr int S_LEN = 2048;
constexpr int D_DIM = 128;
constexpr int NBH   = 64;                     // B*H
constexpr int NKT   = 32;                     // number of 64-key tiles
constexpr size_t TILE_SHORTS = 64 * 128;      // 8192 shorts = 16 KB per K or V^T tile
constexpr size_t PAIR_SHORTS = 2 * TILE_SHORTS;
constexpr size_t WS_NEEDED   = (size_t)NBH * NKT * PAIR_SHORTS * 2;  // 64 MB

typedef __attribute__((ext_vector_type(8))) short short8;  // 8 x bf16
typedef __attribute__((ext_vector_type(4))) float f32x4;   // MFMA acc

__device__ __forceinline__ short f2bf(float f) {
    unsigned u = __builtin_bit_cast(unsigned, f);
    u += 0x7fffu + ((u >> 16) & 1u);
    return (short)(u >> 16);
}

// Swizzled chunk positions (8-short chunks), baked into the GLOBAL tile image
// so that DMA (identity copy) reproduces them in LDS.  (Proven layouts.)
__device__ __forceinline__ int kpos(int dc, int key) { return dc ^ (key & 15); }
__device__ __forceinline__ int vpos(int kc, int d) {
    return kc ^ ((d >> 3) & 7) ^ (d & 7);
}

// ---------------- Preprocess: fp32 K/V -> bf16 swizzled tiles in ws ----------
__global__ __launch_bounds__(256)
void preprocess_kv(const float* __restrict__ K, const float* __restrict__ V,
                   short* __restrict__ ws) {
    __shared__ short sv[128 * 64];   // V^T staging for coalesced global writes
    const int tid = threadIdx.x;
    const int kt  = blockIdx.x;
    const int bh  = blockIdx.y;
    const size_t inbase = ((size_t)bh * S_LEN + (size_t)kt * 64) * D_DIM;
    short* wk = ws + ((size_t)bh * NKT + kt) * PAIR_SHORTS;
    short* wv = wk + TILE_SHORTS;

    for (int it = 0; it < 4; ++it) {
        const int idx = (it * 256 + tid) * 8;
        const int key = idx >> 7, d = idx & 127;
        const float* kp = K + inbase + (size_t)key * D_DIM + d;
        float4 a = *reinterpret_cast<const float4*>(kp);
        float4 b = *reinterpret_cast<const float4*>(kp + 4);
        short8 f;
        f[0]=f2bf(a.x); f[1]=f2bf(a.y); f[2]=f2bf(a.z); f[3]=f2bf(a.w);
        f[4]=f2bf(b.x); f[5]=f2bf(b.y); f[6]=f2bf(b.z); f[7]=f2bf(b.w);
        *reinterpret_cast<short8*>(&wk[key * 128 + (kpos(d >> 3, key) << 3)]) = f;
        const float* vp = V + inbase + (size_t)key * D_DIM + d;
        float4 c = *reinterpret_cast<const float4*>(vp);
        float4 e = *reinterpret_cast<const float4*>(vp + 4);
        float vals[8] = {c.x,c.y,c.z,c.w,e.x,e.y,e.z,e.w};
        for (int j = 0; j < 8; ++j) {
            const int dr = d + j;
            sv[dr * 64 + (vpos(key >> 3, dr) << 3) + (key & 7)] = f2bf(vals[j]);
        }
    }
    __syncthreads();
    for (int it = 0; it < 4; ++it) {
        const int off = (it * 256 + tid) * 8;
        *reinterpret_cast<short8*>(&wv[off]) =
            *reinterpret_cast<const short8*>(&sv[off]);
    }
}

// ---------------- Async copy helpers (global -> LDS, 16B/lane) ---------------
__device__ __forceinline__ void async_copy_1k(const short* gsrc, short* ldst,
                                              int lane) {
    __builtin_amdgcn_global_load_lds(
        (const __attribute__((address_space(1))) void*)(gsrc + lane * 8),
        (__attribute__((address_space(3))) void*)ldst, 16, 0, 0);
}
__device__ __forceinline__ void dma_tile16k(const short* gsrc, short* ldst,
                                            int wid, int lane) {
    for (int i = 0; i < 4; ++i) {
        const int s = wid * 4 + i;               // 16 x 1KB slices, 4 waves
        async_copy_1k(gsrc + s * 512, ldst + s * 512, lane);
    }
}

// ---------------- Main flash-attention kernel --------------------------------
// r3 structure UNCHANGED (256 thr / 4 waves / 64-q tiles / 40 KB LDS /
// 4 blocks/CU / uniform paired (31-x,x) / counted vmcnt A/B/C).
// ONE change: bh-partitioning block-id decode.  hwid%8 picks the XCD;
// bh = ((hwid&7)<<3)|((hwid>>3)&7) puts all 16 x-blocks of a bh on ONE XCD:
//   - 128 blocks/XCD, ALL resident (4/CU x 32 CU), all length-33
//   - pi=0: all 16 blocks of a bh read tiles in lockstep from kt=0
//     (L2 live set ~ 8 bh x 64 KB << 4 MB)
//   - pi=1: nested prefix reads (union <= 4 MB/XCD)
// -> per-XCD ws traffic drops from the full 64 MB sweep to ~the 8 bh it owns.
__global__ __launch_bounds__(256, 4)
void fa_causal_main(const float* __restrict__ Q, const short* __restrict__ ws,
                    float* __restrict__ Out) {
    __shared__ short sK [64 * 128];   // DMA image of K tile (swizzled)
    __shared__ short sVt[128 * 64];   // DMA image of V^T tile (swizzled)
    __shared__ short sP [64 * 64];    // P tile, XOR-swizzled, own region

    const int tid  = threadIdx.x;
    const int wid  = tid >> 6;
    const int lane = tid & 63;
    const int quad = lane >> 4;
    const int l16  = lane & 15;

    // bh-per-XCD decode (bijective on [0,1024)):
    const int hwid = blockIdx.x + (blockIdx.y << 4);
    const int bh   = ((hwid & 7) << 3) | ((hwid >> 3) & 7);
    const int x    = hwid >> 6;       // 0..15; pair (31-x, x): 33 iters/block

    const size_t base = (size_t)bh * S_LEN * D_DIM;
    const short* tiles = ws + (size_t)bh * NKT * PAIR_SHORTS;
    const float scale = 0.08838834764831845f;  // 1/sqrt(128)

    for (int pi = 0; pi < 2; ++pi) {
        const int qt = (pi == 0) ? (31 - x) : x;
        const int q0 = qt * 64;

        // ---- Q loads FIRST (so consuming them waits vmcnt(8), leaving the
        //      8 DMA ops below in flight), then K-DMA(0), V-DMA(0). ----
        float4 qa[4], qb[4];
        {
            const float* qp = Q + base + (size_t)(q0 + wid * 16 + l16) * D_DIM;
            for (int kk = 0; kk < 4; ++kk) {
                const int d0 = kk * 32 + quad * 8;
                qa[kk] = *reinterpret_cast<const float4*>(qp + d0);
                qb[kk] = *reinterpret_cast<const float4*>(qp + d0 + 4);
            }
        }
        dma_tile16k(tiles, sK, wid, lane);
        dma_tile16k(tiles + TILE_SHORTS, sVt, wid, lane);

        // ---- Q fragments (A-layout: m=l16, k=quad*8+j), pre-scaled ----
        short8 q_frag[4];
        for (int kk = 0; kk < 4; ++kk) {
            short8 f;
            f[0]=f2bf(qa[kk].x*scale); f[1]=f2bf(qa[kk].y*scale);
            f[2]=f2bf(qa[kk].z*scale); f[3]=f2bf(qa[kk].w*scale);
            f[4]=f2bf(qb[kk].x*scale); f[5]=f2bf(qb[kk].y*scale);
            f[6]=f2bf(qb[kk].z*scale); f[7]=f2bf(qb[kk].w*scale);
            q_frag[kk] = f;
        }

        f32x4 o_acc[8];
        for (int i = 0; i < 8; ++i) o_acc[i] = f32x4{0.f,0.f,0.f,0.f};
        float m_i[4], l_i[4];
        for (int r = 0; r < 4; ++r) { m_i[r] = -1e30f; l_i[r] = 0.f; }

        for (int kt = 0; kt <= qt; ++kt) {
            // A: drain the 4 oldest vmem ops = K-DMA(kt); keep V-DMA(kt)
            // (the 4 newest) in flight.  lgkm(0) for shuffle/LDS ordering.
            asm volatile("s_waitcnt vmcnt(4) lgkmcnt(0)" ::: "memory");
            __builtin_amdgcn_s_barrier();
            asm volatile("" ::: "memory");

            // ---- S = Q K^T (16 rows x 64 keys per wave) ----
            f32x4 s_acc[4];
            for (int ct = 0; ct < 4; ++ct) {
                const int key = ct * 16 + l16;
                f32x4 acc = f32x4{0.f,0.f,0.f,0.f};
                for (int kk = 0; kk < 4; ++kk) {
                    short8 kf = *reinterpret_cast<const short8*>(
                        &sK[key * 128 + (kpos(kk * 4 + quad, key) << 3)]);
                    acc = __builtin_amdgcn_mfma_f32_16x16x32_bf16(q_frag[kk], kf, acc, 0, 0, 0);
                }
                s_acc[ct] = acc;
            }

            // ---- Causal mask on the diagonal tile ----
            if (kt == qt) {
                for (int ct = 0; ct < 4; ++ct) {
                    const int kg = ct * 16 + l16;
                    for (int r = 0; r < 4; ++r)
                        if (kg > wid * 16 + quad * 4 + r) s_acc[ct][r] = -1e30f;
                }
            }

            // ---- Online softmax (registers + 16-lane shuffles) ----
            float tm[4];
            for (int r = 0; r < 4; ++r)
                tm[r] = fmaxf(fmaxf(s_acc[0][r], s_acc[1][r]),
                              fmaxf(s_acc[2][r], s_acc[3][r]));
            for (int off = 1; off < 16; off <<= 1)
                for (int r = 0; r < 4; ++r)
                    tm[r] = fmaxf(tm[r], __shfl_xor(tm[r], off));
            float alpha[4], m_new[4], rs[4];
            for (int r = 0; r < 4; ++r) {
                m_new[r] = fmaxf(m_i[r], tm[r]);
                alpha[r] = __expf(m_i[r] - m_new[r]);
                rs[r] = 0.f;
            }
            for (int ct = 0; ct < 4; ++ct)
                for (int r = 0; r < 4; ++r) {
                    float p = __expf(s_acc[ct][r] - m_new[r]);
                    s_acc[ct][r] = p;
                    rs[r] += p;
                }
            for (int off = 1; off < 16; off <<= 1)
                for (int r = 0; r < 4; ++r)
                    rs[r] += __shfl_xor(rs[r], off);
            for (int r = 0; r < 4; ++r) {
                l_i[r] = alpha[r] * l_i[r] + rs[r];
                m_i[r] = m_new[r];
            }
            for (int nt = 0; nt < 8; ++nt)
                for (int r = 0; r < 4; ++r)
                    o_acc[nt][r] *= alpha[r];

            // B: __syncthreads -> vmcnt(0) drains V-DMA(kt) (the only
            // outstanding vmem), with the QK+softmax window behind it.
            // Also orders all QK reads of sK before the K-DMA below.
            __syncthreads();

            // K-DMA for kt+1: lands in sK across C, drained at next A.
            if (kt < qt)
                dma_tile16k(tiles + (size_t)(kt + 1) * PAIR_SHORTS, sK, wid, lane);

            // ---- P -> sP (XOR-swizzled; same-wave write->read, no barrier) ----
            for (int ct = 0; ct < 4; ++ct)
                for (int r = 0; r < 4; ++r) {
                    const int row = wid * 16 + quad * 4 + r;
                    const int col = ct * 16 + l16;
                    sP[row * 64 + (((col >> 3) ^ (row & 7)) << 3) + (col & 7)]
                        = f2bf(s_acc[ct][r]);
                }

            // ---- O += P V ----
            {
                const int prow = wid * 16 + l16;
                short8 pf[2];
                for (int k2 = 0; k2 < 2; ++k2)
                    pf[k2] = *reinterpret_cast<const short8*>(
                        &sP[prow * 64 + (((k2 * 4 + quad) ^ (prow & 7)) << 3)]);
                for (int nt = 0; nt < 8; ++nt) {
                    const int vrow = nt * 16 + l16;
                    for (int k2 = 0; k2 < 2; ++k2) {
                        short8 vf = *reinterpret_cast<const short8*>(
                            &sVt[vrow * 64 + (vpos(k2 * 4 + quad, vrow) << 3)]);
                        o_acc[nt] = __builtin_amdgcn_mfma_f32_16x16x32_bf16(pf[k2], vf, o_acc[nt], 0, 0, 0);
                    }
                }
            }

            // C: lgkm-only barrier — orders all PV reads of sVt/sP before the
            // V-DMA below; the in-flight K-DMA(kt+1) is NOT drained here.
            asm volatile("s_waitcnt lgkmcnt(0)" ::: "memory");
            __builtin_amdgcn_s_barrier();
            asm volatile("" ::: "memory");

            // V-DMA for kt+1: drains at B(kt+1) with the QK+softmax window.
            if (kt < qt)
                dma_tile16k(tiles + (size_t)(kt + 1) * PAIR_SHORTS + TILE_SHORTS,
                            sVt, wid, lane);
        }

        // ---- Epilogue ----
        for (int nt = 0; nt < 8; ++nt)
            for (int r = 0; r < 4; ++r) {
                const int qrow = q0 + wid * 16 + quad * 4 + r;
                Out[base + (size_t)qrow * D_DIM + nt * 16 + l16] = o_acc[nt][r] / l_i[r];
            }
    }
}

// ---------------- Fallback (round-2 kernel, used if ws too small) ------------
constexpr int SK_STRIDE  = 136;
constexpr int SVT_STRIDE = 72;
constexpr int SP_STRIDE  = 72;

__global__ __launch_bounds__(256, 4)
void fa_causal_fallback(const float* __restrict__ Q, const float* __restrict__ K,
                        const float* __restrict__ V, float* __restrict__ Out) {
    __shared__ short sK[64 * SK_STRIDE];
    __shared__ short sVt[128 * SVT_STRIDE];
    short* sP = sK;
    const int tid  = threadIdx.x;
    const int wid  = tid >> 6;
    const int lane = tid & 63;
    const int quad = lane >> 4;
    const int l16  = lane & 15;
    const int x  = blockIdx.x;
    const int bh = blockIdx.y;
    const size_t base = (size_t)bh * S_LEN * D_DIM;
    const float scale = 0.08838834764831845f;
    for (int pi = 0; pi < 2; ++pi) {
        const int qt = (pi == 0) ? (31 - x) : x;
        const int q0 = qt * 64;
        short8 q_frag[4];
        {
            const float* qp = Q + base + (size_t)(q0 + wid * 16 + l16) * D_DIM;
            for (int kk = 0; kk < 4; ++kk) {
                const int d0 = kk * 32 + quad * 8;
                float4 a = *reinterpret_cast<const float4*>(qp + d0);
                float4 b = *reinterpret_cast<const float4*>(qp + d0 + 4);
                short8 f;
                f[0]=f2bf(a.x*scale); f[1]=f2bf(a.y*scale);
                f[2]=f2bf(a.z*scale); f[3]=f2bf(a.w*scale);
                f[4]=f2bf(b.x*scale); f[5]=f2bf(b.y*scale);
                f[6]=f2bf(b.z*scale); f[7]=f2bf(b.w*scale);
                q_frag[kk] = f;
            }
        }
        f32x4 o_acc[8];
        for (int i = 0; i < 8; ++i) o_acc[i] = f32x4{0.f,0.f,0.f,0.f};
        float m_i[4], l_i[4];
        for (int r = 0; r < 4; ++r) { m_i[r] = -1e30f; l_i[r] = 0.f; }
        for (int kt = 0; kt <= qt; ++kt) {
            for (int it = 0; it < 4; ++it) {
                const int idx = (it * 256 + tid) * 8;
                const int key = idx >> 7, d = idx & 127;
                const float* kp = K + base + (size_t)(kt * 64 + key) * D_DIM + d;
                float4 a = *reinterpret_cast<const float4*>(kp);
                float4 b = *reinterpret_cast<const float4*>(kp + 4);
                short8 f;
                f[0]=f2bf(a.x); f[1]=f2bf(a.y); f[2]=f2bf(a.z); f[3]=f2bf(a.w);
                f[4]=f2bf(b.x); f[5]=f2bf(b.y); f[6]=f2bf(b.z); f[7]=f2bf(b.w);
                *reinterpret_cast<short8*>(&sK[key * SK_STRIDE + d]) = f;
            }
            for (int it = 0; it < 4; ++it) {
                const int idx = (it * 256 + tid) * 8;
                const int key = idx >> 7, d = idx & 127;
                const int kc = key >> 3, kw = key & 7;
                const float* vp = V + base + (size_t)(kt * 64 + key) * D_DIM + d;
                float4 a = *reinterpret_cast<const float4*>(vp);
                float4 b = *reinterpret_cast<const float4*>(vp + 4);
                float vals[8] = {a.x,a.y,a.z,a.w,b.x,b.y,b.z,b.w};
                const int rc = (d >> 3) & 7;
                const int cs = (kc ^ rc) * 8 + kw;
                for (int j = 0; j < 8; ++j)
                    sVt[(d + j) * SVT_STRIDE + cs] = f2bf(vals[j]);
            }
            __syncthreads();
            f32x4 s_acc[4];
            for (int ct = 0; ct < 4; ++ct) {
                f32x4 acc = f32x4{0.f,0.f,0.f,0.f};
                for (int kk = 0; kk < 4; ++kk) {
                    short8 kf = *reinterpret_cast<const short8*>(
                        &sK[(ct * 16 + l16) * SK_STRIDE + kk * 32 + quad * 8]);
                    acc = __builtin_amdgcn_mfma_f32_16x16x32_bf16(q_frag[kk], kf, acc, 0, 0, 0);
                }
                s_acc[ct] = acc;
            }
            if (kt == qt) {
                for (int ct = 0; ct < 4; ++ct) {
                    const int kg = ct * 16 + l16;
                    for (int r = 0; r < 4; ++r)
                        if (kg > wid * 16 + quad * 4 + r) s_acc[ct][r] = -1e30f;
                }
            }
            float tm[4];
            for (int r = 0; r < 4; ++r)
                tm[r] = fmaxf(fmaxf(s_acc[0][r], s_acc[1][r]),
                              fmaxf(s_acc[2][r], s_acc[3][r]));
            for (int off = 1; off < 16; off <<= 1)
                for (int r = 0; r < 4; ++r)
                    tm[r] = fmaxf(tm[r], __shfl_xor(tm[r], off));
            float alpha[4], m_new[4], rs[4];
            for (int r = 0; r < 4; ++r) {
                m_new[r] = fmaxf(m_i[r], tm[r]);
                alpha[r] = __expf(m_i[r] - m_new[r]);
                rs[r] = 0.f;
            }
            for (int ct = 0; ct < 4; ++ct)
                for (int r = 0; r < 4; ++r) {
                    float p = __expf(s_acc[ct][r] - m_new[r]);
                    s_acc[ct][r] = p;
                    rs[r] += p;
                }
            for (int off = 1; off < 16; off <<= 1)
                for (int r = 0; r < 4; ++r)
                    rs[r] += __shfl_xor(rs[r], off);
            for (int r = 0; r < 4; ++r) {
                l_i[r] = alpha[r] * l_i[r] + rs[r];
                m_i[r] = m_new[r];
            }
            for (int nt = 0; nt < 8; ++nt)
                for (int r = 0; r < 4; ++r)
                    o_acc[nt][r] *= alpha[r];
            __syncthreads();
            for (int ct = 0; ct < 4; ++ct)
                for (int r = 0; r < 4; ++r) {
                    const int row = wid * 16 + quad * 4 + r;
                    const int col = ct * 16 + l16;
                    sP[row * SP_STRIDE + (((col >> 3) ^ ((row >> 2) & 7)) << 3) + (col & 7)]
                        = f2bf(s_acc[ct][r]);
                }
            {
                const int prow = wid * 16 + l16;
                const int pxr  = (prow >> 2) & 7;
                for (int nt = 0; nt < 8; ++nt) {
                    const int vrow = nt * 16 + l16;
                    const int vxr  = (vrow >> 3) & 7;
                    for (int k2 = 0; k2 < 2; ++k2) {
                        const int chunk = k2 * 4 + quad;
                        short8 pf = *reinterpret_cast<const short8*>(
                            &sP[prow * SP_STRIDE + ((chunk ^ pxr) << 3)]);
                        short8 vf = *reinterpret_cast<const short8*>(
                            &sVt[vrow * SVT_STRIDE + ((chunk ^ vxr) << 3)]);
                        o_acc[nt] = __builtin_amdgcn_mfma_f32_16x16x32_bf16(pf, vf, o_acc[nt], 0, 0, 0);
                    }
                }
            }
            __syncthreads();
        }
        for (int nt = 0; nt < 8; ++nt)
            for (int r = 0; r < 4; ++r) {
                const int qrow = q0 + wid * 16 + quad * 4 + r;
                Out[base + (size_t)qrow * D_DIM + nt * 16 + l16] = o_acc[nt][r] / l_i[r];
            }
    }
}

extern "C" void kernel_launch(void* const* d_in, const int* in_sizes, int n_in,
                              void* d_out, int out_size, void* d_ws, size_t ws_size,
                              hipStream_t stream) {
    const float* Q = (const float*)d_in[0];
    const float* K = (const float*)d_in[1];
    const float* V = (const float*)d_in[2];
    float* Out = (float*)d_out;

    if (ws_size >= WS_NEEDED) {
        short* ws = (short*)d_ws;
        preprocess_kv<<<dim3(NKT, NBH), 256, 0, stream>>>(K, V, ws);
        fa_causal_main<<<dim3(16, NBH), 256, 0, stream>>>(Q, ws, Out);
    } else {
        fa_causal_fallback<<<dim3(16, NBH), 256, 0, stream>>>(Q, K, V, Out);
    }
}